// Round 7
// baseline (218.015 us; speedup 1.0000x reference)
//
#include <hip/hip_runtime.h>

// out[n,i,j] = sum_k x[n,i,k] * w[i,j,k] + b[i,j]   (N=128, D=512)
// One block per i; 32 chunks of 16 j-rows, full K. W: glds f32 -> ring-2 LDS
// (self-convert: each wave converts only the rows it gldsed -> ring needs NO
// barriers), convert once -> single swizzled bf16 buf (2 barriers/chunk).
// glds(c+2) issued at TOP of body(c): >=4 glds in flight across all barriers,
// counted vmcnt (never 0 in loop). X loaded straight into MFMA fragments from
// global (no staging). LDS = 64K ring + 16K bf16 = 81920 -> 2 blocks/CU.

#define Dd 512
#define DD (512 * 512)

typedef __attribute__((ext_vector_type(8))) short bf16x8;
typedef __attribute__((ext_vector_type(4))) short bf16x4;
typedef __attribute__((ext_vector_type(4))) float f32x4;

__device__ __forceinline__ short f2bf(float f) {
    unsigned u = __builtin_bit_cast(unsigned, f);
    u += 0x7FFFu + ((u >> 16) & 1u);      // RNE
    return (short)(u >> 16);
}

__device__ __forceinline__ bf16x8 cvt8(float4 a, float4 b) {
    bf16x8 h;
    h[0] = f2bf(a.x); h[1] = f2bf(a.y); h[2] = f2bf(a.z); h[3] = f2bf(a.w);
    h[4] = f2bf(b.x); h[5] = f2bf(b.y); h[6] = f2bf(b.z); h[7] = f2bf(b.w);
    return h;
}

__device__ __forceinline__ void glds16(const float* g, float* l) {
    __builtin_amdgcn_global_load_lds(
        (const __attribute__((address_space(1))) void*)g,
        (__attribute__((address_space(3))) void*)l, 16, 0, 0);
}

__global__ __launch_bounds__(512, 4)
void linear3d_kernel(const float* __restrict__ x,
                     const float* __restrict__ w,
                     const float* __restrict__ b,
                     float* __restrict__ out) {
    const int i    = blockIdx.x;
    const int tid  = threadIdx.x;
    const int lane = tid & 63;
    const int wid  = tid >> 6;            // wave owns n-rows [wid*16, wid*16+16)
    const int row16 = lane & 15;
    const int cg    = lane >> 4;

    __shared__ float f32r[2][8192];       // 64 KB ring (glds dst; wave-private rows)
    __shared__ short b16s[8192];          // 16 KB swizzled bf16 W chunk

    const float* xi = x + (size_t)i * Dd;         // x[n,i,k] = xi[n*DD + k]
    const float* wi = w + (size_t)i * DD;         // w[i,j,k] = wi[j*Dd + k]

// convert-write one float4 (q-th quarter of this wave's 2 rows) into b16s
#define CVTW(V, q) do {                                                        \
    int row_  = 2 * wid + ((q) >> 1);                                          \
    int byte_ = (row_ * 1024 + ((q) & 1) * 512 + lane * 8) ^ ((row_ & 7) << 4);\
    bf16x4 h_ = { f2bf(V.x), f2bf(V.y), f2bf(V.z), f2bf(V.w) };                \
    *(bf16x4*)((char*)b16s + byte_) = h_;                                      \
} while (0)

    // ---- prologue: bias(0), g0->slot0, g1->slot1
    float bias_cur = b[i * Dd + row16];
    #pragma unroll
    for (int q = 0; q < 4; ++q) { int t = wid * 4 + q;
        glds16(wi + t * 256 + lane * 4, &f32r[0][t * 256]); }
    #pragma unroll
    for (int q = 0; q < 4; ++q) { int t = wid * 4 + q;
        glds16(wi + 8192 + t * 256 + lane * 4, &f32r[1][t * 256]); }
    asm volatile("" ::: "memory");        // pin: X loads below stay after glds

    // ---- X batch 0 (fragments s=0,1): lane loads exactly its A-elements
    const float* xrow = xi + (size_t)(wid * 16 + row16) * DD + cg * 8;
    float4 pa0 = *(const float4*)(xrow + 0);
    float4 pa1 = *(const float4*)(xrow + 4);
    float4 pa2 = *(const float4*)(xrow + 32);
    float4 pa3 = *(const float4*)(xrow + 36);

    // ---- conv(0): g0 retired when <=8 outstanding ([g1x4, pa x4] newest)
    asm volatile("s_waitcnt vmcnt(8)" ::: "memory");
    __builtin_amdgcn_sched_barrier(0);
    {
        float4 v0 = *(const float4*)(&f32r[0][wid * 1024 +   0 + lane * 4]);
        float4 v1 = *(const float4*)(&f32r[0][wid * 1024 + 256 + lane * 4]);
        float4 v2 = *(const float4*)(&f32r[0][wid * 1024 + 512 + lane * 4]);
        float4 v3 = *(const float4*)(&f32r[0][wid * 1024 + 768 + lane * 4]);
        CVTW(v0, 0); CVTW(v1, 1); CVTW(v2, 2); CVTW(v3, 3);
    }

    // ---- X batches 1..7 pipelined 1-deep; only X outstanding in these waits
    bf16x8 xf[16];
    #pragma unroll
    for (int r = 0; r < 8; ++r) {
        float4 pb0, pb1, pb2, pb3;
        if (r < 7) {
            const float* xb = xrow + (2 * r + 2) * 32;
            pb0 = *(const float4*)(xb + 0);
            pb1 = *(const float4*)(xb + 4);
            pb2 = *(const float4*)(xb + 32);
            pb3 = *(const float4*)(xb + 36);
        }
        if (r < 7) asm volatile("s_waitcnt vmcnt(4)" ::: "memory");
        else       asm volatile("s_waitcnt vmcnt(0)" ::: "memory");
        __builtin_amdgcn_sched_barrier(0);
        xf[2 * r]     = cvt8(pa0, pa1);
        xf[2 * r + 1] = cvt8(pa2, pa3);
        pa0 = pb0; pa1 = pb1; pa2 = pb2; pa3 = pb3;
    }

    // ---- finish prologue: bf0 writes drained, issue g2->slot0, barrier
    asm volatile("s_waitcnt lgkmcnt(0)" ::: "memory");
    #pragma unroll
    for (int q = 0; q < 4; ++q) { int t = wid * 4 + q;
        glds16(wi + 2 * 8192 + t * 256 + lane * 4, &f32r[0][t * 256]); }
    __builtin_amdgcn_s_barrier();
    __builtin_amdgcn_sched_barrier(0);

    // Body(c): [A0: glds(c+2)->slot c&1 (wave's own rows, read by itself last
    // body); bias(c+1)] [A: 16 MFMA from b16s] [B: 4 stores]
    // [C: counted vmcnt; own-rows f32 ds_read; BARRIER1] [D: cvt->b16s;
    // lgkm0; BARRIER2].  vmcnt counts (worst-case vs load reordering):
    // c=0: [g2x4,bias1,st x4]=9; c=1..29: >=13; c=30: >=9. Never 0.
#define BODY(c, VMSTR, DO_GLDS, DO_CONV, DO_BIAS) do {                         \
    if (DO_GLDS) {                                                             \
        const float* gs_ = wi + (size_t)((c) + 2) * 8192;                      \
        float* lb_ = &f32r[(c) & 1][0];                                        \
        _Pragma("unroll")                                                      \
        for (int q = 0; q < 4; ++q) { int t_ = wid * 4 + q;                    \
            glds16(gs_ + t_ * 256 + lane * 4, lb_ + t_ * 256); }               \
    }                                                                          \
    float biasN_ = bias_cur;                                                   \
    if (DO_BIAS) biasN_ = b[i * Dd + ((c) + 1) * 16 + row16];                  \
    f32x4 accA = {0.f, 0.f, 0.f, 0.f}, accB = {0.f, 0.f, 0.f, 0.f};            \
    _Pragma("unroll")                                                          \
    for (int s = 0; s < 16; s += 2) {                                          \
        int byA_ = (row16 * 1024 + s * 64 + cg * 16) ^ ((row16 & 7) << 4);     \
        int byB_ = (row16 * 1024 + (s + 1) * 64 + cg * 16) ^ ((row16 & 7) << 4);\
        bf16x8 wfA_ = *(const bf16x8*)((const char*)b16s + byA_);              \
        bf16x8 wfB_ = *(const bf16x8*)((const char*)b16s + byB_);              \
        accA = __builtin_amdgcn_mfma_f32_16x16x32_bf16(xf[s], wfA_, accA, 0, 0, 0);       \
        accB = __builtin_amdgcn_mfma_f32_16x16x32_bf16(xf[s + 1], wfB_, accB, 0, 0, 0);   \
    }                                                                          \
    { int j_ = (c) * 16 + row16;                                               \
      _Pragma("unroll")                                                        \
      for (int r_ = 0; r_ < 4; ++r_) {                                         \
          int n_ = wid * 16 + cg * 4 + r_;                                     \
          out[(size_t)i * Dd + (size_t)n_ * DD + j_] =                         \
              accA[r_] + accB[r_] + bias_cur;                                  \
      } }                                                                      \
    if (DO_CONV) {                                                             \
        asm volatile("s_waitcnt " VMSTR ::: "memory");                         \
        __builtin_amdgcn_sched_barrier(0);                                     \
        const float* fb_ = &f32r[((c) + 1) & 1][0];                            \
        float4 v0_ = *(const float4*)(fb_ + wid * 1024 +   0 + lane * 4);      \
        float4 v1_ = *(const float4*)(fb_ + wid * 1024 + 256 + lane * 4);      \
        float4 v2_ = *(const float4*)(fb_ + wid * 1024 + 512 + lane * 4);      \
        float4 v3_ = *(const float4*)(fb_ + wid * 1024 + 768 + lane * 4);      \
        asm volatile("" ::: "memory");                                         \
        __builtin_amdgcn_s_barrier();   /* B1: all waves done reading b16s */  \
        __builtin_amdgcn_sched_barrier(0);                                     \
        CVTW(v0_, 0); CVTW(v1_, 1); CVTW(v2_, 2); CVTW(v3_, 3);                \
        asm volatile("s_waitcnt lgkmcnt(0)" ::: "memory");                     \
        __builtin_amdgcn_s_barrier();   /* B2: new b16s visible */             \
        __builtin_amdgcn_sched_barrier(0);                                     \
    }                                                                          \
    bias_cur = biasN_;                                                         \
} while (0)

    BODY(0, "vmcnt(9)", false, true, true);
    #pragma unroll 1
    for (int c = 1; c <= 29; ++c)
        BODY(c, "vmcnt(13)", true, true, true);
    BODY(30, "vmcnt(9)", false, true, true);
    BODY(31, "vmcnt(0)", false, false, false);

#undef BODY
#undef CVTW
}

extern "C" void kernel_launch(void* const* d_in, const int* in_sizes, int n_in,
                              void* d_out, int out_size, void* d_ws, size_t ws_size,
                              hipStream_t stream) {
    const float* x = (const float*)d_in[0];
    const float* w = (const float*)d_in[1];
    const float* b = (const float*)d_in[2];
    float* out = (float*)d_out;
    linear3d_kernel<<<dim3(Dd), dim3(512), 0, stream>>>(x, w, b, out);
}

// Round 8
// 190.070 us; speedup vs baseline: 1.1470x; 1.1470x over previous
//
#include <hip/hip_runtime.h>

// out[n,i,j] = sum_k x[n,i,k] * w[i,j,k] + b[i,j]   (N=128, D=512)
// One block per i; 32 chunks of 16 j-rows at full K. W: glds f32 -> 2-slot
// ring (64 KB total LDS -- the R5/R6/R7 regressions all used 81920 B = exactly
// half of LDS capacity, likely 1 block/CU; 65536 restores 2 blocks/CU).
// No bf16 buffer, no convert pass: lanes read f32 B-fragments (2x ds_read_b128,
// pre-swizzled-source layout) and convert in-register before MFMA.
// ONE barrier + one counted vmcnt(5) per chunk; glds(c+2) reissued right after
// the barrier into the slot all waves just finished reading.

#define Dd 512
#define DD (512 * 512)

typedef __attribute__((ext_vector_type(8))) short bf16x8;
typedef __attribute__((ext_vector_type(4))) short bf16x4;
typedef __attribute__((ext_vector_type(4))) float f32x4;

__device__ __forceinline__ short f2bf(float f) {
    unsigned u = __builtin_bit_cast(unsigned, f);
    u += 0x7FFFu + ((u >> 16) & 1u);      // RNE
    return (short)(u >> 16);
}

__device__ __forceinline__ bf16x8 cvt8(float4 a, float4 b) {
    bf16x8 h;
    h[0] = f2bf(a.x); h[1] = f2bf(a.y); h[2] = f2bf(a.z); h[3] = f2bf(a.w);
    h[4] = f2bf(b.x); h[5] = f2bf(b.y); h[6] = f2bf(b.z); h[7] = f2bf(b.w);
    return h;
}

__device__ __forceinline__ void glds16(const float* g, float* l) {
    __builtin_amdgcn_global_load_lds(
        (const __attribute__((address_space(1))) void*)g,
        (__attribute__((address_space(3))) void*)l, 16, 0, 0);
}

__global__ __launch_bounds__(512, 4)
void linear3d_kernel(const float* __restrict__ x,
                     const float* __restrict__ w,
                     const float* __restrict__ b,
                     float* __restrict__ out) {
    const int i    = blockIdx.x;
    const int tid  = threadIdx.x;
    const int lane = tid & 63;
    const int wid  = tid >> 6;            // wave owns n-rows [wid*16, wid*16+16)
    const int row16 = lane & 15;
    const int cg    = lane >> 4;
    const int sw    = (row16 & 7) << 4;

    __shared__ float f32r[2][8192];       // 64 KB ring; chunks stored XOR-swizzled

    const float* xi = x + (size_t)i * Dd;         // x[n,i,k] = xi[n*DD + k]
    const float* wi = w + (size_t)i * DD;         // w[i,j,k] = wi[j*Dd + k]

    // glds one 32KB chunk: linear LDS dest, INVERSE-swizzled global source, so
    // LDS[row][off] = W[row][off ^ ((row&7)<<4)]  (m173 pre-swizzle pattern).
#define WGLDS(cidx, slot) do {                                                 \
    const float* gsrc_ = wi + (size_t)(cidx) * 8192;                           \
    _Pragma("unroll")                                                          \
    for (int q = 0; q < 4; ++q) {                                              \
        int t_ = wid * 4 + q; int row_ = t_ >> 1;                              \
        int off_ = (((t_ & 1) * 1024) + lane * 16) ^ ((row_ & 7) << 4);        \
        glds16(gsrc_ + row_ * 512 + (off_ >> 2), &f32r[slot][t_ * 256]);       \
    }                                                                          \
} while (0)

    WGLDS(0, 0);                          // chunk 0 in flight during X staging

    // ---- X staging (R4 pattern), scratch = slot1's first 16 KB
    short* xs = (short*)&f32r[1][0];
    bf16x8 xf[16];
    for (int r = 0; r < 8; ++r) {
        __syncthreads();
        #pragma unroll
        for (int p = 0; p < 4; ++p) {
            int idx4 = tid + p * 512;     // 16 rows x 128 float4
            int row = idx4 >> 7, c4 = idx4 & 127;
            float4 v = *(const float4*)(xi + (size_t)(r * 16 + row) * DD + c4 * 4);
            bf16x4 h = { f2bf(v.x), f2bf(v.y), f2bf(v.z), f2bf(v.w) };
            int byte = (row * 1024 + c4 * 8) ^ ((row & 7) << 4);
            *(bf16x4*)((char*)xs + byte) = h;
        }
        __syncthreads();
        if (wid == r) {
            #pragma unroll
            for (int s = 0; s < 16; ++s) {
                int byte = (row16 * 1024 + s * 64 + cg * 16) ^ sw;
                xf[s] = *(const bf16x8*)((const char*)xs + byte);
            }
        }
    }
    __syncthreads();   // scratch reads done; glds(0) drained & visible

    WGLDS(1, 1);       // slot1 becomes ring slot for chunk 1
    float bias_cur = b[i * Dd + row16];

    // Body(c): [bias(c+1)] [16 MFMA: f32 frag reads + in-reg cvt] [4 stores]
    // [vmcnt(5): glds(c+1) retired -- newer ops are exactly {bias,st x4};
    //  s_barrier] [glds(c+2) -> slot just freed].  No vmcnt(0) in loop.
#define BODY(c, VMSTR, DO_GLDS, DO_BIAS, DO_SYNC) do {                         \
    float biasN_ = bias_cur;                                                   \
    if (DO_BIAS) biasN_ = b[i * Dd + ((c) + 1) * 16 + row16];                  \
    const float* buf_ = &f32r[(c) & 1][0] + row16 * 512;                       \
    const int K0_ = ((cg * 32) ^ sw) >> 2;                                     \
    const int K1_ = ((cg * 32) ^ sw ^ 16) >> 2;                                \
    f32x4 accA = {0.f, 0.f, 0.f, 0.f}, accB = {0.f, 0.f, 0.f, 0.f};            \
    _Pragma("unroll")                                                          \
    for (int s = 0; s < 16; s += 2) {                                          \
        float4 a0_ = *(const float4*)(buf_ + K0_ + s * 32);                    \
        float4 a1_ = *(const float4*)(buf_ + K1_ + s * 32);                    \
        float4 b0_ = *(const float4*)(buf_ + K0_ + (s + 1) * 32);              \
        float4 b1_ = *(const float4*)(buf_ + K1_ + (s + 1) * 32);              \
        accA = __builtin_amdgcn_mfma_f32_16x16x32_bf16(                        \
            xf[s], cvt8(a0_, a1_), accA, 0, 0, 0);                             \
        accB = __builtin_amdgcn_mfma_f32_16x16x32_bf16(                        \
            xf[s + 1], cvt8(b0_, b1_), accB, 0, 0, 0);                         \
    }                                                                          \
    { int j_ = (c) * 16 + row16;                                               \
      _Pragma("unroll")                                                        \
      for (int r_ = 0; r_ < 4; ++r_) {                                         \
          int n_ = wid * 16 + cg * 4 + r_;                                     \
          out[(size_t)n_ * DD + (size_t)i * Dd + j_] =                         \
              accA[r_] + accB[r_] + bias_cur;                                  \
      } }                                                                      \
    bias_cur = biasN_;                                                         \
    if (DO_SYNC) {                                                             \
        asm volatile("s_waitcnt " VMSTR ::: "memory");                         \
        __builtin_amdgcn_s_barrier();                                          \
        __builtin_amdgcn_sched_barrier(0);                                     \
    }                                                                          \
    if (DO_GLDS) {                                                             \
        WGLDS((c) + 2, (c) & 1);                                               \
        __builtin_amdgcn_sched_barrier(0);                                     \
    }                                                                          \
} while (0)

    BODY(0, "vmcnt(5)", true, true, true);
    #pragma unroll 1
    for (int c = 1; c <= 29; ++c)
        BODY(c, "vmcnt(5)", true, true, true);
    BODY(30, "vmcnt(5)", false, true, true);
    BODY(31, "vmcnt(0)", false, false, false);

#undef BODY
#undef WGLDS
}

extern "C" void kernel_launch(void* const* d_in, const int* in_sizes, int n_in,
                              void* d_out, int out_size, void* d_ws, size_t ws_size,
                              hipStream_t stream) {
    const float* x = (const float*)d_in[0];
    const float* w = (const float*)d_in[1];
    const float* b = (const float*)d_in[2];
    float* out = (float*)d_out;
    linear3d_kernel<<<dim3(Dd), dim3(512), 0, stream>>>(x, w, b, out);
}